// Round 1
// baseline (145.327 us; speedup 1.0000x reference)
//
#include <hip/hip_runtime.h>
#include <math.h>

#define Bn   128
#define Rn   1152
#define CIn  8
#define Cn   10
#define On   16
#define BO   2048      // Bn*On
#define CBO  20480     // Cn*BO
#define RC   6         // r's per wave-segment
#define NSEG 192       // 192*6 = 1152
#define PSEG 48        // wg-level partial segments (4 waves reduced per wg)

// ---- transpose x[b][r][i] -> XT[r][g][b][q]  (i = g*4+q), float4 units
__global__ __launch_bounds__(256)
void transpose_x(const float* __restrict__ X, float* __restrict__ XT)
{
    const int r = blockIdx.x;
    const int b = threadIdx.x & 127;
    const int g = threadIdx.x >> 7;
    float4 v = *(const float4*)(X + (size_t)b * (Rn * CIn) + r * CIn + g * 4);
    ((float4*)XT)[r * 256 + g * 128 + b] = v;
}

// ---- pass kernel: wave-autonomous, no LDS in main loop
// wg(256) = 4 waves; wave w of block blk covers (c, bh, seg = segq*4+w)
// lane = local b (0..63); thread owns all 16 o's.
// Grid: 960 = Cn(10) * 2 bh * 48 segq  -> ~3.75 blocks/CU, 4 resident
template<int PASS>
__global__ __launch_bounds__(256, 4)
void pass_kernel(const float* __restrict__ XT, const float* __restrict__ W,
                 const float* __restrict__ Sprev, const float* __restrict__ N2,
                 float* __restrict__ PT, float* __restrict__ PL)
{
    __shared__ float red[4][64][34];   // padded stride 34 -> 34.8 KB

    const int blk  = blockIdx.x;
    const int c    = blk / 96;
    const int rem  = blk - c * 96;
    const int bh   = rem / 48;
    const int segq = rem - bh * 48;
    const int tid  = threadIdx.x;
    const int w    = tid >> 6;
    const int lane = tid & 63;
    const int b    = bh * 64 + lane;
    const int r0   = __builtin_amdgcn_readfirstlane((segq * 4 + w) * RC);

    // per-thread Vsum (pre-scaled by log2e) from previous passes
    float vs[16];
    if (PASS > 1) {
        float coef[PASS];
        #pragma unroll
        for (int t = 0; t < PASS - 1; ++t) {
            const float n2 = N2[t];
            coef[t] = n2 / ((1.0f + n2) * sqrtf(n2)) * 1.4426950408889634f;
        }
        const float* sp = Sprev + c * BO + b * On;
        #pragma unroll
        for (int q = 0; q < 4; ++q) {
            float4 a = make_float4(0.f, 0.f, 0.f, 0.f);
            #pragma unroll
            for (int t = 0; t < PASS - 1; ++t) {
                const float4 s4 = *(const float4*)(sp + t * CBO + q * 4);
                a.x = fmaf(coef[t], s4.x, a.x);
                a.y = fmaf(coef[t], s4.y, a.y);
                a.z = fmaf(coef[t], s4.z, a.z);
                a.w = fmaf(coef[t], s4.w, a.w);
            }
            vs[q * 4 + 0] = a.x; vs[q * 4 + 1] = a.y;
            vs[q * 4 + 2] = a.z; vs[q * 4 + 3] = a.w;
        }
    }

    float tacc[16], lacc[16];
    #pragma unroll
    for (int o = 0; o < 16; ++o) { tacc[o] = 0.0f; lacc[o] = 0.0f; }

    const float4* XT4 = (const float4*)XT;
    for (int rr = 0; rr < RC; ++rr) {
        const int r = r0 + rr;
        const float4 xa = XT4[r * 256 + b];
        const float4 xb = XT4[r * 256 + 128 + b];
        // wave-uniform W block: 128 contiguous floats -> scalar loads
        const int woff = __builtin_amdgcn_readfirstlane((c * Rn + r) * 128);
        const float* wr = W + woff;
        #pragma unroll
        for (int o = 0; o < 16; ++o) {
            float u = xa.x * wr[o];
            u = fmaf(xa.y, wr[16 + o], u);
            u = fmaf(xa.z, wr[32 + o], u);
            u = fmaf(xa.w, wr[48 + o], u);
            u = fmaf(xb.x, wr[64 + o], u);
            u = fmaf(xb.y, wr[80 + o], u);
            u = fmaf(xb.z, wr[96 + o], u);
            u = fmaf(xb.w, wr[112 + o], u);
            if (PASS == 1) {
                tacc[o] += u;
            } else {
                const float e = exp2f(u * vs[o]);
                lacc[o] += e;
                tacc[o] = fmaf(e, u, tacc[o]);
            }
        }
    }

    // wg-level reduce across the 4 waves (4 segs) -> one partial per wg
    #pragma unroll
    for (int o = 0; o < 16; ++o) {
        red[w][lane][o]      = tacc[o];
        red[w][lane][16 + o] = lacc[o];
    }
    __syncthreads();

    {
        const int bl = tid >> 2;          // 0..63
        const int og = tid & 3;           // 0..3
        const int bg = bh * 64 + bl;
        float4 tv, lv;
        float* tp = (float*)&tv;
        float* lp = (float*)&lv;
        #pragma unroll
        for (int q = 0; q < 4; ++q) {
            const int o = og * 4 + q;
            tp[q] = red[0][bl][o] + red[1][bl][o] + red[2][bl][o] + red[3][bl][o];
            lp[q] = red[0][bl][16 + o] + red[1][bl][16 + o] +
                    red[2][bl][16 + o] + red[3][bl][16 + o];
        }
        const int idx = segq * CBO + c * BO + bg * On + og * 4;
        *(float4*)(PT + idx) = tv;
        if (PASS > 1) *(float4*)(PL + idx) = lv;
    }
}

// sum partials over PSEG segs; s = T/L; store S slot; reduce sum(s^2) -> N2 slot
template<int PASS>
__global__ __launch_bounds__(256)
void combine_kernel(const float* __restrict__ PT, const float* __restrict__ PL,
                    float* __restrict__ Sout, float* __restrict__ n2out)
{
    const int i = blockIdx.x * 256 + threadIdx.x;   // 80 blocks * 256 = 20480
    float T = 0.0f, L = 0.0f;
    #pragma unroll
    for (int s = 0; s < PSEG; ++s) T += PT[s * CBO + i];
    if (PASS == 1) {
        L = (float)Rn;
    } else {
        #pragma unroll
        for (int s = 0; s < PSEG; ++s) L += PL[s * CBO + i];
    }
    const float sv = T / L;
    Sout[i] = sv;
    float sq = sv * sv;
    #pragma unroll
    for (int d = 1; d < 64; d <<= 1) sq += __shfl_xor(sq, d);
    __shared__ float red[4];
    if ((threadIdx.x & 63) == 0) red[threadIdx.x >> 6] = sq;
    __syncthreads();
    if (threadIdx.x == 0)
        atomicAdd(n2out, red[0] + red[1] + red[2] + red[3]);
}

__global__ __launch_bounds__(256)
void final_kernel(const float* __restrict__ S, const float* __restrict__ n2p,
                  float* __restrict__ out)
{
    const int i = blockIdx.x * 256 + threadIdx.x;
    const float n2 = *n2p;
    const float coef = n2 / ((1.0f + n2) * sqrtf(n2));
    out[i] = coef * S[i];
}

extern "C" void kernel_launch(void* const* d_in, const int* in_sizes, int n_in,
                              void* d_out, int out_size, void* d_ws, size_t ws_size,
                              hipStream_t stream)
{
    const float* X = (const float*)d_in[0];
    const float* W = (const float*)d_in[1];
    float* ws = (float*)d_ws;
    float* XT = ws;                          // 1,179,648 floats (4.7 MB)
    float* N2 = XT + Rn * Bn * CIn;          // 4 floats
    float* PT = N2 + 4;                      // PSEG*CBO = 983,040
    float* PL = PT + PSEG * CBO;             // PSEG*CBO
    float* S  = PL + PSEG * CBO;             // 3*CBO

    hipMemsetAsync(N2, 0, 16, stream);       // zero n^2 accumulators only

    transpose_x<<<Rn, 256, 0, stream>>>(X, XT);
    pass_kernel<1><<<960, 256, 0, stream>>>(XT, W, S, N2, PT, PL);
    combine_kernel<1><<<80, 256, 0, stream>>>(PT, PL, S + 0 * CBO, N2 + 0);
    pass_kernel<2><<<960, 256, 0, stream>>>(XT, W, S, N2, PT, PL);
    combine_kernel<2><<<80, 256, 0, stream>>>(PT, PL, S + 1 * CBO, N2 + 1);
    pass_kernel<3><<<960, 256, 0, stream>>>(XT, W, S, N2, PT, PL);
    combine_kernel<3><<<80, 256, 0, stream>>>(PT, PL, S + 2 * CBO, N2 + 2);
    final_kernel<<<80, 256, 0, stream>>>(S + 2 * CBO, N2 + 2, (float*)d_out);
}

// Round 2
// 122.567 us; speedup vs baseline: 1.1857x; 1.1857x over previous
//
#include <hip/hip_runtime.h>
#include <math.h>

#define Bn   128
#define Rn   1152
#define CIn  8
#define Cn   10
#define On   16
#define BO   2048      // Bn*On
#define CBO  20480     // Cn*BO
#define RC   12        // r's per wave-segment
#define NSEG 96        // 96*12 = 1152
#define PSEG 24        // wg-level partial segments (4 r-waves reduced per wg)

// ---- transpose x[b][r][i] -> XT[r][g][b][q]  (i = g*4+q), float4 units
__global__ __launch_bounds__(256)
void transpose_x(const float* __restrict__ X, float* __restrict__ XT)
{
    const int r = blockIdx.x;
    const int b = threadIdx.x & 127;
    const int g = threadIdx.x >> 7;
    float4 v = *(const float4*)(X + (size_t)b * (Rn * CIn) + r * CIn + g * 4);
    ((float4*)XT)[r * 256 + g * 128 + b] = v;
}

// ---- pass kernel: wave-autonomous, no LDS in main loop
// wg(512) = 8 waves = 4 r-segs x 2 o-halves.
// wave w: oh = w>>2 (which 8 of the 16 o's), sw = w&3 (r-seg within block)
// lane = local b (0..63); thread owns 8 o's -> tacc[8]/lacc[8]/vs[8].
// Grid: 480 = Cn(10) * 2 bh * 24 segq  (1.875 blocks/CU, 15 waves/CU)
template<int PASS>
__global__ __launch_bounds__(512, 4)
void pass_kernel(const float* __restrict__ XT, const float* __restrict__ W,
                 const float* __restrict__ Sprev, const float* __restrict__ N2,
                 float* __restrict__ PT, float* __restrict__ PL)
{
    __shared__ float red[8][64][18];   // 36.9 KB

    const int blk  = blockIdx.x;
    const int c    = blk / 48;
    const int rem  = blk - c * 48;
    const int bh   = rem / 24;
    const int segq = rem - bh * 24;
    const int tid  = threadIdx.x;
    const int w    = tid >> 6;
    const int lane = tid & 63;
    const int b    = bh * 64 + lane;
    const int oh   = w >> 2;                 // o-half: 0 -> o 0..7, 1 -> o 8..15
    const int sw   = w & 3;                  // r-seg within block
    const int r0   = __builtin_amdgcn_readfirstlane((segq * 4 + sw) * RC);
    const int ohs  = __builtin_amdgcn_readfirstlane(oh * 8);

    // per-thread Vsum (pre-scaled by log2e) from previous passes, 8 o's
    float vs[8];
    if (PASS > 1) {
        float coef[PASS];
        #pragma unroll
        for (int t = 0; t < PASS - 1; ++t) {
            const float n2 = N2[t];
            coef[t] = n2 / ((1.0f + n2) * sqrtf(n2)) * 1.4426950408889634f;
        }
        const float* sp = Sprev + c * BO + b * On + ohs;
        #pragma unroll
        for (int q = 0; q < 2; ++q) {
            float4 a = make_float4(0.f, 0.f, 0.f, 0.f);
            #pragma unroll
            for (int t = 0; t < PASS - 1; ++t) {
                const float4 s4 = *(const float4*)(sp + t * CBO + q * 4);
                a.x = fmaf(coef[t], s4.x, a.x);
                a.y = fmaf(coef[t], s4.y, a.y);
                a.z = fmaf(coef[t], s4.z, a.z);
                a.w = fmaf(coef[t], s4.w, a.w);
            }
            vs[q * 4 + 0] = a.x; vs[q * 4 + 1] = a.y;
            vs[q * 4 + 2] = a.z; vs[q * 4 + 3] = a.w;
        }
    }

    float tacc[8], lacc[8];
    #pragma unroll
    for (int o = 0; o < 8; ++o) { tacc[o] = 0.0f; lacc[o] = 0.0f; }

    const float4* XT4 = (const float4*)XT;
    for (int rr = 0; rr < RC; ++rr) {
        const int r = r0 + rr;
        const float4 xa = XT4[r * 256 + b];
        const float4 xb = XT4[r * 256 + 128 + b];
        // wave-uniform W block: this wave needs 64 of the 128 floats
        const int woff = __builtin_amdgcn_readfirstlane((c * Rn + r) * 128 + ohs);
        const float* wr = W + woff;
        #pragma unroll
        for (int o = 0; o < 8; ++o) {
            float u = xa.x * wr[o];
            u = fmaf(xa.y, wr[16 + o], u);
            u = fmaf(xa.z, wr[32 + o], u);
            u = fmaf(xa.w, wr[48 + o], u);
            u = fmaf(xb.x, wr[64 + o], u);
            u = fmaf(xb.y, wr[80 + o], u);
            u = fmaf(xb.z, wr[96 + o], u);
            u = fmaf(xb.w, wr[112 + o], u);
            if (PASS == 1) {
                tacc[o] += u;
            } else {
                const float e = exp2f(u * vs[o]);
                lacc[o] += e;
                tacc[o] = fmaf(e, u, tacc[o]);
            }
        }
    }

    // wg-level reduce across the 4 r-seg waves (per o-half) -> one partial per wg
    #pragma unroll
    for (int o = 0; o < 8; ++o) {
        red[w][lane][o]     = tacc[o];
        red[w][lane][8 + o] = lacc[o];
    }
    __syncthreads();

    {
        const int oh2  = tid >> 8;        // which o-half to reduce
        const int rem2 = tid & 255;
        const int bl   = rem2 >> 2;       // 0..63
        const int oq   = rem2 & 3;        // 2 o's per thread
        const int bg   = bh * 64 + bl;
        float2 tv, lv;
        float* tp = (float*)&tv;
        float* lp = (float*)&lv;
        #pragma unroll
        for (int q = 0; q < 2; ++q) {
            const int o = oq * 2 + q;
            tp[q] = red[oh2 * 4 + 0][bl][o] + red[oh2 * 4 + 1][bl][o] +
                    red[oh2 * 4 + 2][bl][o] + red[oh2 * 4 + 3][bl][o];
            lp[q] = red[oh2 * 4 + 0][bl][8 + o] + red[oh2 * 4 + 1][bl][8 + o] +
                    red[oh2 * 4 + 2][bl][8 + o] + red[oh2 * 4 + 3][bl][8 + o];
        }
        const int idx = segq * CBO + c * BO + bg * On + oh2 * 8 + oq * 2;
        *(float2*)(PT + idx) = tv;
        if (PASS > 1) *(float2*)(PL + idx) = lv;
    }
}

// sum partials over PSEG segs; s = T/L; store S slot; reduce sum(s^2) -> N2 slot
template<int PASS>
__global__ __launch_bounds__(256)
void combine_kernel(const float* __restrict__ PT, const float* __restrict__ PL,
                    float* __restrict__ Sout, float* __restrict__ n2out)
{
    const int i = blockIdx.x * 256 + threadIdx.x;   // 80 blocks * 256 = 20480
    float T = 0.0f, L = 0.0f;
    #pragma unroll
    for (int s = 0; s < PSEG; ++s) T += PT[s * CBO + i];
    if (PASS == 1) {
        L = (float)Rn;
    } else {
        #pragma unroll
        for (int s = 0; s < PSEG; ++s) L += PL[s * CBO + i];
    }
    const float sv = T / L;
    Sout[i] = sv;
    float sq = sv * sv;
    #pragma unroll
    for (int d = 1; d < 64; d <<= 1) sq += __shfl_xor(sq, d);
    __shared__ float red[4];
    if ((threadIdx.x & 63) == 0) red[threadIdx.x >> 6] = sq;
    __syncthreads();
    if (threadIdx.x == 0)
        atomicAdd(n2out, red[0] + red[1] + red[2] + red[3]);
}

__global__ __launch_bounds__(256)
void final_kernel(const float* __restrict__ S, const float* __restrict__ n2p,
                  float* __restrict__ out)
{
    const int i = blockIdx.x * 256 + threadIdx.x;
    const float n2 = *n2p;
    const float coef = n2 / ((1.0f + n2) * sqrtf(n2));
    out[i] = coef * S[i];
}

extern "C" void kernel_launch(void* const* d_in, const int* in_sizes, int n_in,
                              void* d_out, int out_size, void* d_ws, size_t ws_size,
                              hipStream_t stream)
{
    const float* X = (const float*)d_in[0];
    const float* W = (const float*)d_in[1];
    float* ws = (float*)d_ws;
    float* XT = ws;                          // 1,179,648 floats (4.7 MB)
    float* N2 = XT + Rn * Bn * CIn;          // 4 floats
    float* PT = N2 + 4;                      // PSEG*CBO = 491,520
    float* PL = PT + PSEG * CBO;             // PSEG*CBO
    float* S  = PL + PSEG * CBO;             // 3*CBO

    hipMemsetAsync(N2, 0, 16, stream);       // zero n^2 accumulators only

    transpose_x<<<Rn, 256, 0, stream>>>(X, XT);
    pass_kernel<1><<<480, 512, 0, stream>>>(XT, W, S, N2, PT, PL);
    combine_kernel<1><<<80, 256, 0, stream>>>(PT, PL, S + 0 * CBO, N2 + 0);
    pass_kernel<2><<<480, 512, 0, stream>>>(XT, W, S, N2, PT, PL);
    combine_kernel<2><<<80, 256, 0, stream>>>(PT, PL, S + 1 * CBO, N2 + 1);
    pass_kernel<3><<<480, 512, 0, stream>>>(XT, W, S, N2, PT, PL);
    combine_kernel<3><<<80, 256, 0, stream>>>(PT, PL, S + 2 * CBO, N2 + 2);
    final_kernel<<<80, 256, 0, stream>>>(S + 2 * CBO, N2 + 2, (float*)d_out);
}